// Round 15
// baseline (12696.030 us; speedup 1.0000x reference)
//
#include <hip/hip_runtime.h>
#include <hip/hip_bf16.h>
#include <stdint.h>

// SubLSTM T=1024, B=64, H=512, GATE=3H, L=2 — round 15: r12 fused/staggered
// structure with HALVED exchange domain: 8 groups x 16 blocks, each block owns
// 32 h-cols of both layers. 384 threads = 6 gate waves (16 gate rows each —
// per-wave weights stay 256 VGPR; per-wave MFMA per half unchanged) with the
// r12 round skeleton verbatim:
//   C0{check va0 -> hA, stash xr} -> issue xr' -> B1
//   -> L0 (a0a,a0b,proj0) -> B2 -> issue va1 -> E0 (publish h0_i)
//   -> a1a (cover) -> C1{check va1 -> hB} -> flush pend outs -> B3
//   -> L1 (a1b,proj1) -> issue va0' -> B4 -> E1 (publish h1_{i-1})
// Rationale: the residual ~2.4us/round is max-of-N straggler coupling at the
// two checks (r13 refuted flight-window, r10 refuted vmcnt-drain); halving N
// from 32 to 16 halves the expected group-max jitter.
// Protocol: u64 = (tag32<<32)|(2xbf16), relaxed agent atomics (data IS flag;
// single-copy atomic). Ring depth 4/layer; lock-step bounds skew <=3;
// cross-replay stale accepts bit-identical; 0xAA never matches a wanted tag.
// State: tid<256 owns one L0 cell (tid); tid>=128 owns one L1 cell (tid-128).

#define TSTEPS 1024
#define BATCH  64
#define HID    512
#define GATE   1536
#define GROWS  8
#define NT     384
#define NBLOCKS 128
#define BPG    16          // blocks per group
#define GWORDS 2048        // u64 per group slot tile (8 rows x 512 cols / 2)

typedef unsigned long long u64;
typedef __attribute__((ext_vector_type(8))) short short8;
typedef __attribute__((ext_vector_type(4))) short short4v;
typedef __attribute__((ext_vector_type(4))) float floatx4;

__device__ __forceinline__ float sigmoidf_(float x) { return 1.0f / (1.0f + __expf(-x)); }

__device__ __forceinline__ unsigned short f2bf(float x) {
    union { float f; unsigned u; } v; v.f = x;
    unsigned r = v.u + 0x7FFFu + ((v.u >> 16) & 1u);   // RNE
    return (unsigned short)(r >> 16);
}

__device__ __forceinline__ short8 load_frag(const float* p) {
    floatx4 a = *(const floatx4*)p;
    floatx4 b = *(const floatx4*)(p + 4);
    short8 r;
#pragma unroll
    for (int j = 0; j < 4; ++j) { r[j] = (short)f2bf(a[j]); r[j+4] = (short)f2bf(b[j]); }
    return r;
}

__device__ __forceinline__ u64 ring_ld(const u64* p) {
    return __hip_atomic_load(p, __ATOMIC_RELAXED, __HIP_MEMORY_SCOPE_AGENT);
}
__device__ __forceinline__ void ring_st(u64* p, u64 v) {
    __hip_atomic_store(p, v, __ATOMIC_RELAXED, __HIP_MEMORY_SCOPE_AGENT);
}

// ---- preamble: x f32 -> bf16 ----
__global__ __launch_bounds__(256) void xconvert(const float* __restrict__ x,
                                                unsigned short* __restrict__ xb) {
    const size_t i = ((size_t)blockIdx.x*256 + threadIdx.x) * 8;
    floatx4 a = *(const floatx4*)(x + i);
    floatx4 b = *(const floatx4*)(x + i + 4);
    short8 p;
#pragma unroll
    for (int j = 0; j < 4; ++j) { p[j] = (short)f2bf(a[j]); p[j+4] = (short)f2bf(b[j]); }
    *(short8*)(xb + i) = p;
}

__global__ __launch_bounds__(NT, 1) void sublstm_fused(
    const unsigned short* __restrict__ xb,
    const float* __restrict__ W,
    const float* __restrict__ R,
    const float* __restrict__ bi,
    const float* __restrict__ bh,
    const float* __restrict__ fw,
    const float* __restrict__ h0,
    const float* __restrict__ c0,
    u64* __restrict__ ring,        // [lyr 2][slot 4][grp 8][blk 16][row 8][unit 16]
    float* __restrict__ out)
{
    const int tid  = threadIdx.x;
    const int lane = tid & 63;
    const int wid  = tid >> 6;            // 0..5 gate waves (gate=wid>>1, half=wid&1)
    const int bid  = blockIdx.x;
    const int g    = bid & 7;             // batch group
    const int bidx = bid >> 3;            // 0..15: 32-col slice
    const int col0 = bidx << 5;

    __shared__ __align__(16) unsigned short x_tile[16][520];
    __shared__ __align__(16) unsigned short hA[16][520];    // h0_{i-1}
    __shared__ __align__(16) unsigned short hB[16][520];    // h1_{i-2}
    __shared__ float proj[3][16][33];

    for (int i = tid; i < 16*520; i += NT) {
        ((unsigned short*)x_tile)[i] = 0;
        ((unsigned short*)hA)[i] = 0;
        ((unsigned short*)hB)[i] = 0;
    }
    __syncthreads();   // zero-init visible before staging

    const int lrow = lane & 15;
    const int lk   = (lane >> 4) << 3;

    // ---- weights: each gate wave owns 16 gate rows of both layers ----
    short8 wf0[16], rf0[16], wf1[16], rf1[16];
    float bias0 = 0.f, bias1 = 0.f;
    {
        const int wrow = (wid >> 1)*HID + col0 + (wid & 1)*16 + lrow;
#pragma unroll
        for (int kc = 0; kc < 16; ++kc) {
            wf0[kc] = load_frag(W + (size_t)wrow*HID + kc*32 + lk);
            rf0[kc] = load_frag(R + (size_t)wrow*HID + kc*32 + lk);
            wf1[kc] = load_frag(W + ((size_t)GATE + wrow)*HID + kc*32 + lk);
            rf1[kc] = load_frag(R + ((size_t)GATE + wrow)*HID + kc*32 + lk);
        }
        bias0 = bi[wrow] + bh[wrow];
        bias1 = bi[GATE + wrow] + bh[GATE + wrow];
    }

    // ---- state: tid<256 -> L0 cell tid; tid>=128 -> L1 cell tid-128 ----
    const bool hasL0 = (tid < 256);
    const bool hasL1 = (tid >= 128);
    const int c0i = tid, c1i = tid - 128;
    const int sr0 = (c0i >> 5) & 7, sc0 = c0i & 31;
    const int sr1 = (c1i >> 5) & 7, sc1 = c1i & 31;
    float fgv0 = 0.f, fgv1 = 0.f, creg0 = 0.f, creg1 = 0.f;
    if (hasL0) {
        fgv0 = sigmoidf_(fw[col0 + sc0]);
        creg0 = c0[((size_t)g*GROWS + sr0)*HID + col0 + sc0];
    }
    if (hasL1) {
        fgv1 = sigmoidf_(fw[(size_t)HID + col0 + sc1]);
        creg1 = c0[((size_t)BATCH + g*GROWS + sr1)*HID + col0 + sc1];
    }

    // ---- prologue: stage x_0 and h0 tiles ----
    {
        const unsigned short* xp = xb + (size_t)g*GROWS*HID;
        for (int w = tid; w < GROWS*HID/8; w += NT) {
            const int r = w >> 6, c8 = (w & 63) << 3;
            *(short8*)(&x_tile[r][c8]) = *(const short8*)(xp + (size_t)r*HID + c8);
        }
        const float* hp0 = h0 + (size_t)g*GROWS*HID;
        const float* hp1 = h0 + ((size_t)BATCH + g*GROWS)*HID;
        for (int w = tid; w < GROWS*HID/4; w += NT) {
            const int r = w >> 7, c4 = (w & 127) << 2;
            floatx4 va_ = *(const floatx4*)(hp0 + (size_t)r*HID + c4);
            floatx4 vb_ = *(const floatx4*)(hp1 + (size_t)r*HID + c4);
            short4v pa, pb;
#pragma unroll
            for (int j = 0; j < 4; ++j) { pa[j] = (short)f2bf(va_[j]); pb[j] = (short)f2bf(vb_[j]); }
            *(short4v*)(&hA[r][c4]) = pa;
            *(short4v*)(&hB[r][c4]) = pb;
        }
    }
    __syncthreads();

    int budget = 1 << 22;
    int pend_t = -1;                // L1 out-store deferral (tid>=128)
    float pend_h = 0.f, pend_c = 0.f;
    u64 va0[6], va1[6];
    short8 xr0, xr1;                // xr1 only valid for tid<128
    {
        const unsigned short* xp = xb + (size_t)BATCH*HID + (size_t)g*GROWS*HID;  // x_1
        xr0 = *(const short8*)(xp + (size_t)(tid >> 6)*HID + ((tid & 63) << 3));
        if (tid < 128) {
            const int w1 = tid + NT;
            xr1 = *(const short8*)(xp + (size_t)(w1 >> 6)*HID + ((w1 & 63) << 3));
        }
    }

    for (int i = 0; i <= TSTEPS; ++i) {
        // ==== C0: consume h0_{i-1} -> hA; stash x_i ====
        if (i >= 1) {
            const unsigned want = (unsigned)i;
            const u64* rb0 = ring + ((size_t)((i - 1) & 3)*8 + g)*GWORDS;
            unsigned stale = 0;
#pragma unroll
            for (int k = 0; k < 6; ++k) {
                const int w = tid + k*NT;
                if (w < GWORDS && (unsigned)(va0[k] >> 32) != want) stale |= (1u << k);
            }
            int pass = 0;
            while (__any((int)(stale != 0)) && budget > 0) {
                if (pass++) __builtin_amdgcn_s_sleep(1);
#pragma unroll
                for (int k = 0; k < 6; ++k)
                    if (stale & (1u << k)) va0[k] = ring_ld(rb0 + tid + k*NT);
#pragma unroll
                for (int k = 0; k < 6; ++k)
                    if (stale & (1u << k))
                        if ((unsigned)(va0[k] >> 32) == want) stale &= ~(1u << k);
                --budget;
            }
#pragma unroll
            for (int k = 0; k < 6; ++k) {
                const int w = tid + k*NT;
                if (w < GWORDS) {
                    const int b = w >> 7, r = (w >> 4) & 7, u = w & 15;
                    *(unsigned*)(&hA[r][b*32 + u*2]) = (unsigned)va0[k];
                }
            }
            if (i < TSTEPS) {
                *(short8*)(&x_tile[tid >> 6][(tid & 63) << 3]) = xr0;
                if (tid < 128) {
                    const int w1 = tid + NT;
                    *(short8*)(&x_tile[w1 >> 6][(w1 & 63) << 3]) = xr1;
                }
            }
        }
        // issue xr' <- x_{i+1} (full round to drain)
        if (i + 1 < TSTEPS) {
            const unsigned short* xp = xb + ((size_t)(i + 1)*BATCH + g*GROWS)*HID;
            xr0 = *(const short8*)(xp + (size_t)(tid >> 6)*HID + ((tid & 63) << 3));
            if (tid < 128) {
                const int w1 = tid + NT;
                xr1 = *(const short8*)(xp + (size_t)(w1 >> 6)*HID + ((w1 & 63) << 3));
            }
        }
        __syncthreads();   // B1

        // ==== L0 half: a0a = x@W0 + a0b = hA@R0 + proj0 ====
        if (i < TSTEPS) {
            floatx4 a0a = {0,0,0,0}, a0b = {0,0,0,0};
#pragma unroll
            for (int kc = 0; kc < 16; ++kc) {
                short8 afx = *(const short8*)(&x_tile[lrow][kc*32 + lk]);
                short8 afh = *(const short8*)(&hA[lrow][kc*32 + lk]);
                a0a = __builtin_amdgcn_mfma_f32_16x16x32_bf16(afx, wf0[kc], a0a, 0, 0, 0);
                a0b = __builtin_amdgcn_mfma_f32_16x16x32_bf16(afh, rf0[kc], a0b, 0, 0, 0);
            }
            const int erow0 = (lane >> 4) << 2, ecol = (wid & 1)*16 + lrow;
#pragma unroll
            for (int q = 0; q < 4; ++q)
                proj[wid >> 1][erow0 + q][ecol] = sigmoidf_(a0a[q] + a0b[q] + bias0);
        }
        __syncthreads();   // B2

        // ==== issue va1 (h1_{i-2}) BEFORE E0 stores ====
        if (i >= 2) {
            const u64* rb1 = ring + (size_t)4*8*GWORDS + ((size_t)((i - 2) & 3)*8 + g)*GWORDS;
#pragma unroll
            for (int k = 0; k < 6; ++k) {
                const int w = tid + k*NT;
                if (w < GWORDS) va1[k] = ring_ld(rb1 + w);
            }
        }
        __builtin_amdgcn_sched_barrier(0);

        // ==== E0: L0 state update + publish h0_i ====
        if (hasL0 && i < TSTEPS) {
            const float ig = proj[0][sr0][sc0];
            const float og = proj[1][sr0][sc0];
            const float zz = proj[2][sr0][sc0];
            const float c_ = creg0*fgv0 + zz - ig;
            creg0 = c_;
            const float h_ = sigmoidf_(c_) - og;
            const unsigned hu = __float_as_uint(h_);
            const unsigned pu = (unsigned)__builtin_amdgcn_ds_swizzle((int)hu, 0x041F);
            unsigned pay;
            asm volatile("v_cvt_pk_bf16_f32 %0, %1, %2"
                         : "=v"(pay) : "v"(h_), "v"(__uint_as_float(pu)));
            if (!(sc0 & 1)) {
                const size_t off = (((size_t)(i & 3)*8 + g)*BPG + bidx)*128
                                 + sr0*16 + (sc0 >> 1);
                ring_st(ring + off, (u64)pay | ((u64)(unsigned)(i + 1) << 32));
            }
            if (i == TSTEPS - 1) {   // L0 finals (one-time direct store)
                const size_t fo = (size_t)TSTEPS*BATCH*HID
                                + ((size_t)g*GROWS + sr0)*HID + col0 + sc0;
                out[fo] = h_;
                out[fo + (size_t)2*BATCH*HID] = creg0;
            }
        }
        __builtin_amdgcn_sched_barrier(0);

        // ==== a1a = hA @ W1 (flight cover for va1) ====
        floatx4 a1a = {0,0,0,0};
        if (i >= 1) {
#pragma unroll
            for (int kc = 0; kc < 16; ++kc) {
                short8 afh = *(const short8*)(&hA[lrow][kc*32 + lk]);
                a1a = __builtin_amdgcn_mfma_f32_16x16x32_bf16(afh, wf1[kc], a1a, 0, 0, 0);
            }
        }
        __builtin_amdgcn_sched_barrier(0);

        // ==== C1: consume h1_{i-2} -> hB ====
        if (i >= 2) {
            const unsigned want = (unsigned)(i - 1);
            const u64* rb1 = ring + (size_t)4*8*GWORDS + ((size_t)((i - 2) & 3)*8 + g)*GWORDS;
            unsigned stale = 0;
#pragma unroll
            for (int k = 0; k < 6; ++k) {
                const int w = tid + k*NT;
                if (w < GWORDS && (unsigned)(va1[k] >> 32) != want) stale |= (1u << k);
            }
            int pass = 0;
            while (__any((int)(stale != 0)) && budget > 0) {
                if (pass++) __builtin_amdgcn_s_sleep(1);
#pragma unroll
                for (int k = 0; k < 6; ++k)
                    if (stale & (1u << k)) va1[k] = ring_ld(rb1 + tid + k*NT);
#pragma unroll
                for (int k = 0; k < 6; ++k)
                    if (stale & (1u << k))
                        if ((unsigned)(va1[k] >> 32) == want) stale &= ~(1u << k);
                --budget;
            }
#pragma unroll
            for (int k = 0; k < 6; ++k) {
                const int w = tid + k*NT;
                if (w < GWORDS) {
                    const int b = w >> 7, r = (w >> 4) & 7, u = w & 15;
                    *(unsigned*)(&hB[r][b*32 + u*2]) = (unsigned)va1[k];
                }
            }
        }
        // flush deferred L1 out stores (drains under L1+E1+next C0)
        if (pend_t >= 0) {
            out[((size_t)pend_t*BATCH + g*GROWS + sr1)*HID + col0 + sc1] = pend_h;
            if (pend_t == TSTEPS - 1) {
                const size_t fo = (size_t)TSTEPS*BATCH*HID
                                + ((size_t)BATCH + g*GROWS + sr1)*HID + col0 + sc1;
                out[fo] = pend_h;
                out[fo + (size_t)2*BATCH*HID] = pend_c;
            }
            pend_t = -1;
        }
        __syncthreads();   // B3

        // ==== L1 half: a1b = hB@R1 + proj1 ====
        if (i >= 1) {
            floatx4 a1b = {0,0,0,0};
#pragma unroll
            for (int kc = 0; kc < 16; ++kc) {
                short8 afb = *(const short8*)(&hB[lrow][kc*32 + lk]);
                a1b = __builtin_amdgcn_mfma_f32_16x16x32_bf16(afb, rf1[kc], a1b, 0, 0, 0);
            }
            const int erow0 = (lane >> 4) << 2, ecol = (wid & 1)*16 + lrow;
#pragma unroll
            for (int q = 0; q < 4; ++q)
                proj[wid >> 1][erow0 + q][ecol] = sigmoidf_(a1a[q] + a1b[q] + bias1);
        }
        // issue va0' (h0_i, published at E0 this round)
        if (i < TSTEPS) {
            const u64* rb0n = ring + ((size_t)(i & 3)*8 + g)*GWORDS;
#pragma unroll
            for (int k = 0; k < 6; ++k) {
                const int w = tid + k*NT;
                if (w < GWORDS) va0[k] = ring_ld(rb0n + w);
            }
        }
        __syncthreads();   // B4

        // ==== E1: L1 state update + publish h1_{i-1}; defer out ====
        if (hasL1 && i >= 1) {
            const int t = i - 1;
            const float ig = proj[0][sr1][sc1];
            const float og = proj[1][sr1][sc1];
            const float zz = proj[2][sr1][sc1];
            const float c_ = creg1*fgv1 + zz - ig;
            creg1 = c_;
            const float h_ = sigmoidf_(c_) - og;
            const unsigned hu = __float_as_uint(h_);
            const unsigned pu = (unsigned)__builtin_amdgcn_ds_swizzle((int)hu, 0x041F);
            unsigned pay;
            asm volatile("v_cvt_pk_bf16_f32 %0, %1, %2"
                         : "=v"(pay) : "v"(h_), "v"(__uint_as_float(pu)));
            if (!(sc1 & 1)) {
                const size_t off = (size_t)4*8*GWORDS
                                 + (((size_t)(t & 3)*8 + g)*BPG + bidx)*128
                                 + sr1*16 + (sc1 >> 1);
                ring_st(ring + off, (u64)pay | ((u64)(unsigned)(t + 1) << 32));
            }
            pend_t = t; pend_h = h_; pend_c = c_;
        }
    }

    // ---- post-loop: flush the last deferred L1 stores ----
    if (pend_t >= 0) {
        out[((size_t)pend_t*BATCH + g*GROWS + sr1)*HID + col0 + sc1] = pend_h;
        if (pend_t == TSTEPS - 1) {
            const size_t fo = (size_t)TSTEPS*BATCH*HID
                            + ((size_t)BATCH + g*GROWS + sr1)*HID + col0 + sc1;
            out[fo] = pend_h;
            out[fo + (size_t)2*BATCH*HID] = pend_c;
        }
    }
}

extern "C" void kernel_launch(void* const* d_in, const int* in_sizes, int n_in,
                              void* d_out, int out_size, void* d_ws, size_t ws_size,
                              hipStream_t stream)
{
    (void)in_sizes; (void)n_in; (void)out_size; (void)ws_size;
    const float* x  = (const float*)d_in[0];
    const float* h0 = (const float*)d_in[1];
    const float* c0 = (const float*)d_in[2];
    const float* W  = (const float*)d_in[3];
    const float* R  = (const float*)d_in[4];
    const float* bi = (const float*)d_in[5];
    const float* bh = (const float*)d_in[6];
    const float* fw = (const float*)d_in[7];
    float* out = (float*)d_out;

    u64* ring = (u64*)d_ws;                                             // 1 MB
    unsigned short* xbuf = (unsigned short*)((char*)d_ws + (2u << 20)); // 64 MB

    hipMemsetAsync(d_ws, 0, (size_t)2*4*8*GWORDS*8, stream);  // hygiene

    xconvert<<<dim3(TSTEPS*BATCH*HID/(256*8)), dim3(256), 0, stream>>>(x, xbuf);

    sublstm_fused<<<dim3(NBLOCKS), dim3(NT), 0, stream>>>(
        xbuf, W, R, bi, bh, fw, h0, c0, ring, out);
}